// Round 1
// baseline (530.462 us; speedup 1.0000x reference)
//
#include <hip/hip_runtime.h>

// RopelessMLA on MI355X (gfx950).
// B=2 S=2048 D=1024 H=16 L=512 DH=64. All heavy math in bf16 MFMA (f32 accum).

typedef __attribute__((ext_vector_type(4))) float f32x4;
typedef __attribute__((ext_vector_type(8))) unsigned short u16x8;
typedef __attribute__((ext_vector_type(4))) unsigned short u16x4;
typedef __attribute__((ext_vector_type(8))) __bf16 bf16x8;

__device__ __forceinline__ unsigned short f2bf(float f) {
  unsigned int u = __builtin_bit_cast(unsigned int, f);
  u += 0x7FFFu + ((u >> 16) & 1u);   // RNE; inputs finite
  return (unsigned short)(u >> 16);
}

__device__ __forceinline__ f32x4 mfma16(u16x8 a, u16x8 b, f32x4 c) {
  return __builtin_amdgcn_mfma_f32_16x16x32_bf16(
      __builtin_bit_cast(bf16x8, a), __builtin_bit_cast(bf16x8, b), c, 0, 0, 0);
}

__device__ __forceinline__ void gload_lds16(const void* g, void* l) {
  __builtin_amdgcn_global_load_lds(
      (const __attribute__((address_space(1))) unsigned int*)g,
      (__attribute__((address_space(3))) unsigned int*)l, 16, 0, 0);
}

// ---------------- f32 -> bf16 convert (vectorized) ----------------
__global__ __launch_bounds__(256) void cvt_bf16(const float* __restrict__ in,
                                                unsigned short* __restrict__ out,
                                                int n4) {
  int i = blockIdx.x * 256 + threadIdx.x;
  int stride = gridDim.x * 256;
  for (; i < n4; i += stride) {
    float4 v = ((const float4*)in)[i];
    u16x4 o;
    o[0] = f2bf(v.x); o[1] = f2bf(v.y); o[2] = f2bf(v.z); o[3] = f2bf(v.w);
    ((u16x4*)out)[i] = o;
  }
}

// ---------------- W_uk [1024][512] f32 -> W_ukT [512][1024] bf16 ----------------
__global__ __launch_bounds__(256) void transpose_cvt(const float* __restrict__ in,
                                                     unsigned short* __restrict__ out) {
  __shared__ float t[64][65];
  int r0 = blockIdx.y * 64, c0 = blockIdx.x * 64;
  int lr = threadIdx.x >> 4, lc = (threadIdx.x & 15) * 4;
#pragma unroll
  for (int i = 0; i < 4; i++) {
    int row = lr + i * 16;
    float4 v = *(const float4*)(in + (size_t)(r0 + row) * 512 + c0 + lc);
    t[row][lc] = v.x; t[row][lc + 1] = v.y; t[row][lc + 2] = v.z; t[row][lc + 3] = v.w;
  }
  __syncthreads();
#pragma unroll
  for (int i = 0; i < 4; i++) {
    int oc = lr + i * 16;
    u16x4 o;
    o[0] = f2bf(t[lc + 0][oc]); o[1] = f2bf(t[lc + 1][oc]);
    o[2] = f2bf(t[lc + 2][oc]); o[3] = f2bf(t[lc + 3][oc]);
    *(u16x4*)(out + (size_t)(c0 + oc) * 1024 + r0 + lc) = o;
  }
}

// ---------------- GEMM-BT: C[M,N] = A[M,K] * B[N,K]^T (bf16 in, f32 acc) ----------
// 128x128 tile, BK=32, 256 thr (4 waves 2x2), global_load_lds staging,
// XOR swizzle ((row>>1)&3)<<4 on LDS byte addr to spread b128 reads across banks.
template <int F32OUT>
__global__ __launch_bounds__(256, 2)
void gemm_bt(const unsigned short* __restrict__ A, const unsigned short* __restrict__ B,
             void* __restrict__ Cout, int M, int N, int K, int lda, int ldb, int ldc,
             long za, long zb, long zc) {
  __shared__ __align__(16) unsigned short sA[128 * 32];
  __shared__ __align__(16) unsigned short sB[128 * 32];
  A += za * blockIdx.z;
  B += zb * blockIdx.z;
  const int tid = threadIdx.x;
  const int w = tid >> 6, ln = tid & 63;
  const int m0 = blockIdx.y * 128, n0 = blockIdx.x * 128;
  const int wm = (w >> 1) * 64, wn = (w & 1) * 64;
  const int c16 = ln & 15, g = ln >> 4;
  f32x4 zero = {0.f, 0.f, 0.f, 0.f};
  f32x4 acc[4][4];
#pragma unroll
  for (int i = 0; i < 4; i++)
#pragma unroll
    for (int j = 0; j < 4; j++) acc[i][j] = zero;

  for (int kt = 0; kt < K; kt += 32) {
#pragma unroll
    for (int l = 0; l < 2; l++) {
      int c = l * 256 + tid;
      int row = c >> 2;                       // 0..127
      int physb = (c & 3) << 4;               // byte in row (phys)
      int colb = physb ^ (((row >> 1) & 3) << 4);  // undo swizzle for source
      gload_lds16(A + (size_t)(m0 + row) * lda + kt + (colb >> 1),
                  (char*)sA + (l * 256 + w * 64) * 16);
      gload_lds16(B + (size_t)(n0 + row) * ldb + kt + (colb >> 1),
                  (char*)sB + (l * 256 + w * 64) * 16);
    }
    __syncthreads();
    u16x8 af[4], bfr[4];
#pragma unroll
    for (int i = 0; i < 4; i++) {
      int ra = wm + i * 16 + c16;
      int rb = wn + i * 16 + c16;
      af[i]  = *(const u16x8*)((const char*)sA + ((ra * 64 + g * 16) ^ (((ra >> 1) & 3) << 4)));
      bfr[i] = *(const u16x8*)((const char*)sB + ((rb * 64 + g * 16) ^ (((rb >> 1) & 3) << 4)));
    }
#pragma unroll
    for (int i = 0; i < 4; i++)
#pragma unroll
      for (int j = 0; j < 4; j++) acc[i][j] = mfma16(af[i], bfr[j], acc[i][j]);
    __syncthreads();
  }
  const int row0 = m0 + wm + g * 4;
  const int col0 = n0 + wn + c16;
  if (F32OUT) {
    float* C = (float*)Cout + zc * blockIdx.z;
#pragma unroll
    for (int i = 0; i < 4; i++)
#pragma unroll
      for (int j = 0; j < 4; j++)
#pragma unroll
        for (int r = 0; r < 4; r++)
          C[(size_t)(row0 + i * 16 + r) * ldc + col0 + j * 16] = acc[i][j][r];
  } else {
    unsigned short* C = (unsigned short*)Cout + zc * blockIdx.z;
#pragma unroll
    for (int i = 0; i < 4; i++)
#pragma unroll
      for (int j = 0; j < 4; j++)
#pragma unroll
        for (int r = 0; r < 4; r++)
          C[(size_t)(row0 + i * 16 + r) * ldc + col0 + j * 16] = f2bf(acc[i][j][r]);
  }
}

// ---------------- LayerNorm rows of 512: c_f32 -> (f32 out, bf16 out) -------------
__global__ __launch_bounds__(256)
void ln_rows(const float* __restrict__ cin, const float* __restrict__ gamma,
             const float* __restrict__ beta, float* __restrict__ of32,
             unsigned short* __restrict__ obf) {
  int row = blockIdx.x * 4 + (threadIdx.x >> 6);
  int ln = threadIdx.x & 63;
  const float* r = cin + (size_t)row * 512 + ln * 8;
  float4 a = *(const float4*)r;
  float4 b = *(const float4*)(r + 4);
  float xv[8] = {a.x, a.y, a.z, a.w, b.x, b.y, b.z, b.w};
  float s = 0.f, q = 0.f;
#pragma unroll
  for (int j = 0; j < 8; j++) { s += xv[j]; q += xv[j] * xv[j]; }
#pragma unroll
  for (int m = 1; m < 64; m <<= 1) { s += __shfl_xor(s, m); q += __shfl_xor(q, m); }
  float mu = s * (1.f / 512.f);
  float var = q * (1.f / 512.f) - mu * mu;
  float rs = rsqrtf(var + 1e-5f);
  float gm[8], bt[8];
  *(float4*)&gm[0] = *(const float4*)(gamma + ln * 8);
  *(float4*)&gm[4] = *(const float4*)(gamma + ln * 8 + 4);
  *(float4*)&bt[0] = *(const float4*)(beta + ln * 8);
  *(float4*)&bt[4] = *(const float4*)(beta + ln * 8 + 4);
  float o[8];
#pragma unroll
  for (int j = 0; j < 8; j++) o[j] = (xv[j] - mu) * rs * gm[j] + bt[j];
  float4 o0 = {o[0], o[1], o[2], o[3]}, o1 = {o[4], o[5], o[6], o[7]};
  *(float4*)(of32 + (size_t)row * 512 + ln * 8) = o0;
  *(float4*)(of32 + (size_t)row * 512 + ln * 8 + 4) = o1;
  u16x8 ob;
#pragma unroll
  for (int j = 0; j < 8; j++) ob[j] = f2bf(o[j]);
  *(u16x8*)(obf + (size_t)row * 512 + ln * 8) = ob;
}

// ---------------- Flash attention ------------------------------------------------
// grid (32 qtiles, 32 b*h). 256 thr. Per wave: 16 q rows, Q(16x512) in registers.
// K tiles of 32 rows staged bf16 in swizzled LDS; V tile transposed into padded LDS.
__global__ __launch_bounds__(256, 2)
void mla_attn(const unsigned short* __restrict__ qlat,   // [H][4096][512]
              const unsigned short* __restrict__ ckv,    // [4096][512]
              const unsigned short* __restrict__ vmat,   // [4096][1024]
              unsigned short* __restrict__ ctx) {        // [4096][1024]
  __shared__ __align__(16) unsigned short sK[32 * 512];  // swizzled: ^((t&7)<<4)
  __shared__ __align__(16) unsigned short sVT[64 * 40];  // [d][t], pad stride 40
  __shared__ __align__(16) unsigned short sP[4][16 * 40];
  const int tid = threadIdx.x, w = tid >> 6, ln = tid & 63;
  const int b = blockIdx.y >> 4, h = blockIdx.y & 15;
  const int q0 = blockIdx.x * 64;
  const int g = ln >> 4, c16 = ln & 15;

  u16x8 qf[16];
  {
    const unsigned short* qp =
        qlat + ((size_t)h * 4096 + b * 2048 + q0 + w * 16 + c16) * 512 + g * 8;
#pragma unroll
    for (int ks = 0; ks < 16; ks++) qf[ks] = *(const u16x8*)(qp + ks * 32);
  }
  f32x4 zero = {0.f, 0.f, 0.f, 0.f};
  f32x4 o[4];
  o[0] = zero; o[1] = zero; o[2] = zero; o[3] = zero;
  float mrow[4], lrow[4];
#pragma unroll
  for (int r = 0; r < 4; r++) { mrow[r] = -__builtin_inff(); lrow[r] = 0.f; }
  const float SC = 0.18033688011112042f;  // (1/8) * log2(e)
  const int ntile = 2 * blockIdx.x + 2;
  const unsigned short* kbase = ckv + (size_t)b * 2048 * 512;
  const unsigned short* vbase = vmat + (size_t)b * 2048 * 1024 + h * 64;

  for (int t32 = 0; t32 < ntile; t32++) {
    const int t0 = t32 * 32;
    // stage K tile (32KB) via global_load_lds, source pre-swizzled
#pragma unroll
    for (int rd = 0; rd < 8; rd++) {
      int phys = (rd * 256 + tid) * 16;
      int trow = phys >> 10;
      int colb = (phys ^ ((trow & 7) << 4)) & 1023;
      gload_lds16(kbase + (size_t)(t0 + trow) * 512 + (colb >> 1),
                  (char*)sK + (rd * 256 + w * 64) * 16);
    }
    // stage V^T (32 t-rows x 64 d) into padded LDS
    {
      int trow = tid & 31;
      int d8 = (tid >> 5) * 8;
      u16x8 vv = *(const u16x8*)(vbase + (size_t)(t0 + trow) * 1024 + d8);
#pragma unroll
      for (int j = 0; j < 8; j++) sVT[(d8 + j) * 40 + trow] = vv[j];
    }
    __syncthreads();
    // S = Q K^T  (2 n-tiles of 16 t-cols, K reduce 512)
    f32x4 s[2];
#pragma unroll
    for (int nt = 0; nt < 2; nt++) {
      f32x4 a = zero;
      int tl = nt * 16 + c16;
      int sw = (tl & 7) << 4;
      int base = tl * 1024 + g * 16;
#pragma unroll
      for (int ks = 0; ks < 16; ks++) {
        u16x8 kf = *(const u16x8*)((const char*)sK + ((base + ks * 64) ^ sw));
        a = mfma16(qf[ks], kf, a);
      }
      s[nt] = a;
    }
    // online softmax (C layout: col=c16 -> t, row=g*4+r -> q)
    float p[2][4], al[4];
#pragma unroll
    for (int r = 0; r < 4; r++) {
      int qg = q0 + w * 16 + g * 4 + r;
      float v0 = (t0 + c16 <= qg) ? s[0][r] * SC : -1e30f;
      float v1 = (t0 + 16 + c16 <= qg) ? s[1][r] * SC : -1e30f;
      float rm = fmaxf(v0, v1);
      rm = fmaxf(rm, __shfl_xor(rm, 1));
      rm = fmaxf(rm, __shfl_xor(rm, 2));
      rm = fmaxf(rm, __shfl_xor(rm, 4));
      rm = fmaxf(rm, __shfl_xor(rm, 8));
      float m2 = fmaxf(mrow[r], rm);
      float alpha = exp2f(mrow[r] - m2);
      float p0 = exp2f(v0 - m2), p1 = exp2f(v1 - m2);
      float rsum = p0 + p1;
      rsum += __shfl_xor(rsum, 1);
      rsum += __shfl_xor(rsum, 2);
      rsum += __shfl_xor(rsum, 4);
      rsum += __shfl_xor(rsum, 8);
      lrow[r] = lrow[r] * alpha + rsum;
      mrow[r] = m2;
      al[r] = alpha;
      p[0][r] = p0; p[1][r] = p1;
    }
#pragma unroll
    for (int dt = 0; dt < 4; dt++) {
      o[dt][0] *= al[0]; o[dt][1] *= al[1]; o[dt][2] *= al[2]; o[dt][3] *= al[3];
    }
    // P -> LDS (bf16), per-wave region
    unsigned short* Pw = &sP[w][0];
#pragma unroll
    for (int nt = 0; nt < 2; nt++)
#pragma unroll
      for (int r = 0; r < 4; r++)
        Pw[(g * 4 + r) * 40 + nt * 16 + c16] = f2bf(p[nt][r]);
    // O += P V  (A-frag from P, B-frag from V^T)
    {
      u16x8 pa = *(const u16x8*)((const char*)Pw + c16 * 80 + g * 16);
#pragma unroll
      for (int dt = 0; dt < 4; dt++) {
        u16x8 vb = *(const u16x8*)((const char*)sVT + (dt * 16 + c16) * 80 + g * 16);
        o[dt] = mfma16(pa, vb, o[dt]);
      }
    }
    __syncthreads();
  }
#pragma unroll
  for (int r = 0; r < 4; r++) {
    float inv = 1.f / lrow[r];
    unsigned short* cp =
        ctx + (size_t)(b * 2048 + q0 + w * 16 + g * 4 + r) * 1024 + h * 64 + c16;
#pragma unroll
    for (int dt = 0; dt < 4; dt++) cp[dt * 16] = f2bf(o[dt][r] * inv);
  }
}

// ---------------- launch ----------------------------------------------------------
extern "C" void kernel_launch(void* const* d_in, const int* in_sizes, int n_in,
                              void* d_out, int out_size, void* d_ws, size_t ws_size,
                              hipStream_t stream) {
  const float* x    = (const float*)d_in[0];
  const float* Wq   = (const float*)d_in[1];
  const float* Wdkv = (const float*)d_in[2];
  const float* Wuk  = (const float*)d_in[3];
  const float* Wuv  = (const float*)d_in[4];
  const float* Wo   = (const float*)d_in[5];
  const float* gam  = (const float*)d_in[6];
  const float* bet  = (const float*)d_in[7];
  float* out_f = (float*)d_out;                       // [4096][1024]
  float* ckv_f = out_f + (size_t)4096 * 1024;         // [4096][512]

  char* ws = (char*)d_ws;
  unsigned short* xb     = (unsigned short*)(ws);              // 8 MB
  unsigned short* wq_b   = (unsigned short*)(ws + 8388608);    // 2 MB
  unsigned short* wdkv_b = (unsigned short*)(ws + 10485760);   // 1 MB
  unsigned short* wukT_b = (unsigned short*)(ws + 11534336);   // 1 MB
  unsigned short* wuv_b  = (unsigned short*)(ws + 12582912);   // 1 MB
  unsigned short* wo_b   = (unsigned short*)(ws + 13631488);   // 2 MB
  unsigned short* akt_b  = (unsigned short*)(ws + 15728640);   // 1 MB  [512][1024]
  unsigned short* ckv_b  = (unsigned short*)(ws + 16777216);   // 4 MB  [4096][512]
  float*          c_f    = (float*)(ws + 20971520);            // 8 MB  [4096][512]
  unsigned short* qlat   = (unsigned short*)(ws + 29360128);   // 64 MB [16][4096][512]
  unsigned short* v_b    = (unsigned short*)(ws + 96468992);   // 8 MB  [4096][1024]
  unsigned short* ctx_b  = (unsigned short*)(ws + 104857600);  // 8 MB  [4096][1024]

  cvt_bf16<<<2048, 256, 0, stream>>>(x, xb, 1048576);
  cvt_bf16<<<1024, 256, 0, stream>>>(Wq, wq_b, 262144);
  cvt_bf16<<<512, 256, 0, stream>>>(Wdkv, wdkv_b, 131072);
  cvt_bf16<<<512, 256, 0, stream>>>(Wuv, wuv_b, 131072);
  cvt_bf16<<<1024, 256, 0, stream>>>(Wo, wo_b, 262144);
  transpose_cvt<<<dim3(8, 16), 256, 0, stream>>>(Wuk, wukT_b);

  // c = x @ W_dkv^T  (f32 out)
  gemm_bt<1><<<dim3(4, 32), 256, 0, stream>>>(xb, wdkv_b, c_f, 4096, 512, 1024,
                                              1024, 1024, 512, 0, 0, 0);
  // LayerNorm -> c_kv (f32 to d_out, bf16 to ws)
  ln_rows<<<1024, 256, 0, stream>>>(c_f, gam, bet, ckv_f, ckv_b);
  // AK^T = W_uk^T @ W_q^T   [512][1024]
  gemm_bt<0><<<dim3(8, 4), 256, 0, stream>>>(wukT_b, wq_b, akt_b, 512, 1024, 1024,
                                             1024, 1024, 1024, 0, 0, 0);
  // q_lat[h] = x[:, h*64:+64] @ (AK^T[:, h*64:+64])^T    K=64, z = head
  gemm_bt<0><<<dim3(4, 32, 16), 256, 0, stream>>>(xb, akt_b, qlat, 4096, 512, 64,
                                                  1024, 1024, 512, 64, 64, 2097152);
  // v = c_kv @ W_uv^T   [4096][1024]
  gemm_bt<0><<<dim3(8, 32), 256, 0, stream>>>(ckv_b, wuv_b, v_b, 4096, 1024, 512,
                                              512, 512, 1024, 0, 0, 0);
  // flash attention -> ctx
  mla_attn<<<dim3(32, 32), 256, 0, stream>>>(qlat, ckv_b, v_b, ctx_b);
  // out = ctx @ W_o^T  (f32 to d_out)
  gemm_bt<1><<<dim3(8, 32), 256, 0, stream>>>(ctx_b, wo_b, out_f, 4096, 1024, 1024,
                                              1024, 1024, 1024, 0, 0, 0);
}

// Round 2
// 257.433 us; speedup vs baseline: 2.0606x; 2.0606x over previous
//
#include <hip/hip_runtime.h>

// RopelessMLA on MI355X (gfx950).
// B=2 S=2048 D=1024 H=16 L=512 DH=64.
// Key reformulation: scores = q @ (AK @ c_kv^T) = q @ k_abs^T with
// k_abs = c_kv @ AK^T (one dense GEMM). Attention is then standard causal
// MHA with head dim 64 -> 8x fewer attention FLOPs than (q@AK)@c_kv^T.

typedef __attribute__((ext_vector_type(4))) float f32x4;
typedef __attribute__((ext_vector_type(8))) unsigned short u16x8;
typedef __attribute__((ext_vector_type(4))) unsigned short u16x4;
typedef __attribute__((ext_vector_type(8))) __bf16 bf16x8;

__device__ __forceinline__ unsigned short f2bf(float f) {
  unsigned int u = __builtin_bit_cast(unsigned int, f);
  u += 0x7FFFu + ((u >> 16) & 1u);   // RNE; inputs finite
  return (unsigned short)(u >> 16);
}

__device__ __forceinline__ f32x4 mfma16(u16x8 a, u16x8 b, f32x4 c) {
  return __builtin_amdgcn_mfma_f32_16x16x32_bf16(
      __builtin_bit_cast(bf16x8, a), __builtin_bit_cast(bf16x8, b), c, 0, 0, 0);
}

__device__ __forceinline__ void gload_lds16(const void* g, void* l) {
  __builtin_amdgcn_global_load_lds(
      (const __attribute__((address_space(1))) unsigned int*)g,
      (__attribute__((address_space(3))) unsigned int*)l, 16, 0, 0);
}

// ---------------- f32 -> bf16 convert (vectorized) ----------------
__global__ __launch_bounds__(256) void cvt_bf16(const float* __restrict__ in,
                                                unsigned short* __restrict__ out,
                                                int n4) {
  int i = blockIdx.x * 256 + threadIdx.x;
  int stride = gridDim.x * 256;
  for (; i < n4; i += stride) {
    float4 v = ((const float4*)in)[i];
    u16x4 o;
    o[0] = f2bf(v.x); o[1] = f2bf(v.y); o[2] = f2bf(v.z); o[3] = f2bf(v.w);
    ((u16x4*)out)[i] = o;
  }
}

// ---------------- W_uk [1024][512] f32 -> W_ukT [512][1024] bf16 ----------------
__global__ __launch_bounds__(256) void transpose_cvt(const float* __restrict__ in,
                                                     unsigned short* __restrict__ out) {
  __shared__ float t[64][65];
  int r0 = blockIdx.y * 64, c0 = blockIdx.x * 64;
  int lr = threadIdx.x >> 4, lc = (threadIdx.x & 15) * 4;
#pragma unroll
  for (int i = 0; i < 4; i++) {
    int row = lr + i * 16;
    float4 v = *(const float4*)(in + (size_t)(r0 + row) * 512 + c0 + lc);
    t[row][lc] = v.x; t[row][lc + 1] = v.y; t[row][lc + 2] = v.z; t[row][lc + 3] = v.w;
  }
  __syncthreads();
#pragma unroll
  for (int i = 0; i < 4; i++) {
    int oc = lr + i * 16;
    u16x4 o;
    o[0] = f2bf(t[lc + 0][oc]); o[1] = f2bf(t[lc + 1][oc]);
    o[2] = f2bf(t[lc + 2][oc]); o[3] = f2bf(t[lc + 3][oc]);
    *(u16x4*)(out + (size_t)(c0 + oc) * 1024 + r0 + lc) = o;
  }
}

// ---------------- GEMM-BT: C[M,N] = A[M,K] * B[N,K]^T (bf16 in, f32 acc) ----------
// MODE 0: bf16 out; MODE 1: f32 out; MODE 2: bf16 transposed out C^T (ldc = trans ld)
template <int MODE>
__global__ __launch_bounds__(256, 2)
void gemm_bt(const unsigned short* __restrict__ A, const unsigned short* __restrict__ B,
             void* __restrict__ Cout, int M, int N, int K, int lda, int ldb, int ldc) {
  __shared__ __align__(16) unsigned short sA[128 * 32];
  __shared__ __align__(16) unsigned short sB[128 * 32];
  const int tid = threadIdx.x;
  const int w = tid >> 6, ln = tid & 63;
  const int m0 = blockIdx.y * 128, n0 = blockIdx.x * 128;
  const int wm = (w >> 1) * 64, wn = (w & 1) * 64;
  const int c16 = ln & 15, g = ln >> 4;
  f32x4 zero = {0.f, 0.f, 0.f, 0.f};
  f32x4 acc[4][4];
#pragma unroll
  for (int i = 0; i < 4; i++)
#pragma unroll
    for (int j = 0; j < 4; j++) acc[i][j] = zero;

  for (int kt = 0; kt < K; kt += 32) {
#pragma unroll
    for (int l = 0; l < 2; l++) {
      int c = l * 256 + tid;
      int row = c >> 2;                       // 0..127
      int physb = (c & 3) << 4;               // byte in row (phys)
      int colb = physb ^ (((row >> 1) & 3) << 4);  // undo swizzle for source
      gload_lds16(A + (size_t)(m0 + row) * lda + kt + (colb >> 1),
                  (char*)sA + (l * 256 + w * 64) * 16);
      gload_lds16(B + (size_t)(n0 + row) * ldb + kt + (colb >> 1),
                  (char*)sB + (l * 256 + w * 64) * 16);
    }
    __syncthreads();
    u16x8 af[4], bfr[4];
#pragma unroll
    for (int i = 0; i < 4; i++) {
      int ra = wm + i * 16 + c16;
      int rb = wn + i * 16 + c16;
      af[i]  = *(const u16x8*)((const char*)sA + ((ra * 64 + g * 16) ^ (((ra >> 1) & 3) << 4)));
      bfr[i] = *(const u16x8*)((const char*)sB + ((rb * 64 + g * 16) ^ (((rb >> 1) & 3) << 4)));
    }
#pragma unroll
    for (int i = 0; i < 4; i++)
#pragma unroll
      for (int j = 0; j < 4; j++) acc[i][j] = mfma16(af[i], bfr[j], acc[i][j]);
    __syncthreads();
  }
  const int row0 = m0 + wm + g * 4;
  const int col0 = n0 + wn + c16;
  if (MODE == 1) {
    float* C = (float*)Cout;
#pragma unroll
    for (int i = 0; i < 4; i++)
#pragma unroll
      for (int j = 0; j < 4; j++)
#pragma unroll
        for (int r = 0; r < 4; r++)
          C[(size_t)(row0 + i * 16 + r) * ldc + col0 + j * 16] = acc[i][j][r];
  } else if (MODE == 0) {
    unsigned short* C = (unsigned short*)Cout;
#pragma unroll
    for (int i = 0; i < 4; i++)
#pragma unroll
      for (int j = 0; j < 4; j++)
#pragma unroll
        for (int r = 0; r < 4; r++)
          C[(size_t)(row0 + i * 16 + r) * ldc + col0 + j * 16] = f2bf(acc[i][j][r]);
  } else {  // transposed bf16: C^T[col][row], 4 consecutive rows per lane
    unsigned short* C = (unsigned short*)Cout;
#pragma unroll
    for (int i = 0; i < 4; i++)
#pragma unroll
      for (int j = 0; j < 4; j++) {
        u16x4 t4;
#pragma unroll
        for (int r = 0; r < 4; r++) t4[r] = f2bf(acc[i][j][r]);
        *(u16x4*)(C + (size_t)(col0 + j * 16) * ldc + row0 + i * 16) = t4;
      }
  }
}

// ---------------- LayerNorm rows of 512: c_f32 -> (f32 out, bf16 out) -------------
__global__ __launch_bounds__(256)
void ln_rows(const float* __restrict__ cin, const float* __restrict__ gamma,
             const float* __restrict__ beta, float* __restrict__ of32,
             unsigned short* __restrict__ obf) {
  int row = blockIdx.x * 4 + (threadIdx.x >> 6);
  int ln = threadIdx.x & 63;
  const float* r = cin + (size_t)row * 512 + ln * 8;
  float4 a = *(const float4*)r;
  float4 b = *(const float4*)(r + 4);
  float xv[8] = {a.x, a.y, a.z, a.w, b.x, b.y, b.z, b.w};
  float s = 0.f, q = 0.f;
#pragma unroll
  for (int j = 0; j < 8; j++) { s += xv[j]; q += xv[j] * xv[j]; }
#pragma unroll
  for (int m = 1; m < 64; m <<= 1) { s += __shfl_xor(s, m); q += __shfl_xor(q, m); }
  float mu = s * (1.f / 512.f);
  float var = q * (1.f / 512.f) - mu * mu;
  float rs = rsqrtf(var + 1e-5f);
  float gm[8], bt[8];
  *(float4*)&gm[0] = *(const float4*)(gamma + ln * 8);
  *(float4*)&gm[4] = *(const float4*)(gamma + ln * 8 + 4);
  *(float4*)&bt[0] = *(const float4*)(beta + ln * 8);
  *(float4*)&bt[4] = *(const float4*)(beta + ln * 8 + 4);
  float o[8];
#pragma unroll
  for (int j = 0; j < 8; j++) o[j] = (xv[j] - mu) * rs * gm[j] + bt[j];
  float4 o0 = {o[0], o[1], o[2], o[3]}, o1 = {o[4], o[5], o[6], o[7]};
  *(float4*)(of32 + (size_t)row * 512 + ln * 8) = o0;
  *(float4*)(of32 + (size_t)row * 512 + ln * 8 + 4) = o1;
  u16x8 ob;
#pragma unroll
  for (int j = 0; j < 8; j++) ob[j] = f2bf(o[j]);
  *(u16x8*)(obf + (size_t)row * 512 + ln * 8) = ob;
}

// ---------------- Flash attention (DH=64, causal, fixed-max softmax) -------------
// grid (16 qblocks, 32 b*h), 512 thr = 8 waves x 16 q-rows -> 128 q rows/block.
// t-tiles of 128: K [128][64] and V^T [64][128] staged via swizzled-source
// global_load_lds. Fixed max M0: p = exp2(s*SC - M0); no running max/rescale;
// per-lane lsum reduced once at the end.
__global__ __launch_bounds__(512, 4)
void mla_attn2(const unsigned short* __restrict__ kabs,  // [4096][1024] (t, h*64+d)
               const unsigned short* __restrict__ xq,    // [4096][1024] Q = x (bf16)
               const unsigned short* __restrict__ vT,    // [1024][4096] (h*64+d, t)
               unsigned short* __restrict__ ctx) {       // [4096][1024]
  __shared__ __align__(16) unsigned short sK[128 * 64];    // [t][d] swz ^((t&7)<<4)
  __shared__ __align__(16) unsigned short sVT[64 * 128];   // [d][t] swz ^((d&7)<<4)
  __shared__ __align__(16) unsigned short sP[8][16 * 136]; // per-wave [q][t] pad 136
  const int tid = threadIdx.x, w = tid >> 6, ln = tid & 63;
  const int g = ln >> 4, c16 = ln & 15;
  const int b = blockIdx.y >> 4, h = blockIdx.y & 15;
  const int qb = 15 - blockIdx.x;       // long blocks first
  const int q0 = qb * 128;
  const int qw = q0 + w * 16;           // wave's first q row
  const size_t rowb = (size_t)b * 2048;

  u16x8 qf[2];
  {
    const unsigned short* qp = xq + (rowb + qw + c16) * 1024 + h * 64 + g * 8;
    qf[0] = *(const u16x8*)(qp);
    qf[1] = *(const u16x8*)(qp + 32);
  }
  f32x4 zero = {0.f, 0.f, 0.f, 0.f};
  f32x4 o[4] = {zero, zero, zero, zero};
  float lsum[4] = {0.f, 0.f, 0.f, 0.f};
  const float SC = 0.18033688011112042f;  // (1/8) * log2(e)
  const float M0 = 8.f;
  unsigned short* Pw = &sP[w][0];

  for (int tt = 0; tt <= qb; tt++) {
    const int t0 = tt * 128;
    // stage K [128t][64d] (16KB) and V^T [64d][128t] (16KB), swizzled source
#pragma unroll
    for (int i = 0; i < 2; i++) {
      int c2 = i * 512 + tid;
      int t = c2 >> 3, pc = c2 & 7;
      int sc = pc ^ (t & 7);
      gload_lds16(kabs + (rowb + t0 + t) * 1024 + h * 64 + sc * 8,
                  (char*)sK + (i * 512 + w * 64) * 16);
    }
#pragma unroll
    for (int i = 0; i < 2; i++) {
      int c2 = i * 512 + tid;
      int d = c2 >> 4, pc = c2 & 15;
      int sc = pc ^ (d & 7);
      gload_lds16(vT + (size_t)(h * 64 + d) * 4096 + rowb + t0 + sc * 8,
                  (char*)sVT + (i * 512 + w * 64) * 16);
    }
    __syncthreads();
    // S = Q K^T  (8 nt-tiles of 16 t, reduction 64)
    f32x4 s[8];
#pragma unroll
    for (int nt = 0; nt < 8; nt++) {
      int t = nt * 16 + c16;
      int sw = (t & 7) << 4;
      const char* kb = (const char*)sK + t * 128;
      f32x4 a = zero;
      a = mfma16(qf[0], *(const u16x8*)(kb + ((g * 16) ^ sw)), a);
      a = mfma16(qf[1], *(const u16x8*)(kb + ((64 + g * 16) ^ sw)), a);
      s[nt] = a;
    }
    // fixed-max softmax: p = exp2(s*SC - M0); masked -> 0
    if (tt != qb) {
#pragma unroll
      for (int nt = 0; nt < 8; nt++)
#pragma unroll
        for (int r = 0; r < 4; r++) {
          float p = exp2f(s[nt][r] * SC - M0);
          lsum[r] += p;
          s[nt][r] = p;
        }
    } else {
#pragma unroll
      for (int nt = 0; nt < 8; nt++) {
        int tcol = t0 + nt * 16 + c16;
#pragma unroll
        for (int r = 0; r < 4; r++) {
          float p = (tcol <= qw + g * 4 + r) ? exp2f(s[nt][r] * SC - M0) : 0.f;
          lsum[r] += p;
          s[nt][r] = p;
        }
      }
    }
    // P -> per-wave LDS (bf16)
#pragma unroll
    for (int nt = 0; nt < 8; nt++)
#pragma unroll
      for (int r = 0; r < 4; r++)
        Pw[(g * 4 + r) * 136 + nt * 16 + c16] = f2bf(s[nt][r]);
    // O += P V  (A from sP, B from sVT)
#pragma unroll
    for (int ks = 0; ks < 4; ks++) {
      u16x8 pa = *(const u16x8*)((const char*)Pw + c16 * 272 + ks * 64 + g * 16);
#pragma unroll
      for (int dt = 0; dt < 4; dt++) {
        int d = dt * 16 + c16;
        const char* vb = (const char*)sVT + d * 256 + ((ks * 64 + g * 16) ^ ((d & 7) << 4));
        o[dt] = mfma16(pa, *(const u16x8*)vb, o[dt]);
      }
    }
    __syncthreads();
  }
#pragma unroll
  for (int r = 0; r < 4; r++) {
    float t = lsum[r];
    t += __shfl_xor(t, 1); t += __shfl_xor(t, 2);
    t += __shfl_xor(t, 4); t += __shfl_xor(t, 8);
    float inv = 1.f / t;
    unsigned short* cp = ctx + (rowb + qw + g * 4 + r) * 1024 + h * 64 + c16;
#pragma unroll
    for (int dt = 0; dt < 4; dt++) cp[dt * 16] = f2bf(o[dt][r] * inv);
  }
}

// ---------------- launch ----------------------------------------------------------
extern "C" void kernel_launch(void* const* d_in, const int* in_sizes, int n_in,
                              void* d_out, int out_size, void* d_ws, size_t ws_size,
                              hipStream_t stream) {
  const float* x    = (const float*)d_in[0];
  const float* Wq   = (const float*)d_in[1];
  const float* Wdkv = (const float*)d_in[2];
  const float* Wuk  = (const float*)d_in[3];
  const float* Wuv  = (const float*)d_in[4];
  const float* Wo   = (const float*)d_in[5];
  const float* gam  = (const float*)d_in[6];
  const float* bet  = (const float*)d_in[7];
  float* out_f = (float*)d_out;                       // [4096][1024]
  float* ckv_f = out_f + (size_t)4096 * 1024;         // [4096][512]

  char* ws = (char*)d_ws;
  unsigned short* xb     = (unsigned short*)(ws);              // 8 MB  [4096][1024]
  unsigned short* wq_b   = (unsigned short*)(ws + 8388608);    // 2 MB  [1024][1024]
  unsigned short* wdkv_b = (unsigned short*)(ws + 10485760);   // 1 MB  [512][1024]
  unsigned short* wukT_b = (unsigned short*)(ws + 11534336);   // 1 MB  [512][1024]
  unsigned short* wuv_b  = (unsigned short*)(ws + 12582912);   // 1 MB  [1024][512]
  unsigned short* wo_b   = (unsigned short*)(ws + 13631488);   // 2 MB  [1024][1024]
  unsigned short* akt_b  = (unsigned short*)(ws + 15728640);   // 1 MB  [1024][512]
  unsigned short* ckv_b  = (unsigned short*)(ws + 16777216);   // 4 MB  [4096][512]
  float*          c_f    = (float*)(ws + 20971520);            // 8 MB  [4096][512]
  unsigned short* kabs   = (unsigned short*)(ws + 29360128);   // 8 MB  [4096][1024]
  unsigned short* vT     = (unsigned short*)(ws + 37748736);   // 8 MB  [1024][4096]
  unsigned short* ctx_b  = (unsigned short*)(ws + 46137344);   // 8 MB  [4096][1024]

  cvt_bf16<<<2048, 256, 0, stream>>>(x, xb, 1048576);
  cvt_bf16<<<1024, 256, 0, stream>>>(Wq, wq_b, 262144);
  cvt_bf16<<<512, 256, 0, stream>>>(Wdkv, wdkv_b, 131072);
  cvt_bf16<<<512, 256, 0, stream>>>(Wuv, wuv_b, 131072);
  cvt_bf16<<<1024, 256, 0, stream>>>(Wo, wo_b, 262144);
  transpose_cvt<<<dim3(8, 16), 256, 0, stream>>>(Wuk, wukT_b);

  // c = x @ W_dkv^T  (f32 out)
  gemm_bt<1><<<dim3(4, 32), 256, 0, stream>>>(xb, wdkv_b, c_f, 4096, 512, 1024,
                                              1024, 1024, 512);
  // LayerNorm -> c_kv (f32 to d_out, bf16 to ws)
  ln_rows<<<1024, 256, 0, stream>>>(c_f, gam, bet, ckv_f, ckv_b);
  // AK[hd][l] = sum_m Wq[hd][m] Wuk[m][l]   -> [1024][512]
  gemm_bt<0><<<dim3(4, 8), 256, 0, stream>>>(wq_b, wukT_b, akt_b, 1024, 512, 1024,
                                             1024, 1024, 512);
  // k_abs = c_kv @ AK^T  -> [4096][1024]
  gemm_bt<0><<<dim3(8, 32), 256, 0, stream>>>(ckv_b, akt_b, kabs, 4096, 1024, 512,
                                              512, 512, 1024);
  // v^T = (c_kv @ W_uv^T)^T  -> [1024][4096]
  gemm_bt<2><<<dim3(8, 32), 256, 0, stream>>>(ckv_b, wuv_b, vT, 4096, 1024, 512,
                                              512, 512, 4096);
  // flash attention (DH=64, causal) -> ctx
  mla_attn2<<<dim3(16, 32), 512, 0, stream>>>(kabs, xb, vT, ctx_b);
  // out = ctx @ W_o^T  (f32 out)
  gemm_bt<1><<<dim3(8, 32), 256, 0, stream>>>(ctx_b, wo_b, out_f, 4096, 1024, 1024,
                                              1024, 1024, 1024);
}